// Round 7
// baseline (322.485 us; speedup 1.0000x reference)
//
#include <hip/hip_runtime.h>
#include <hip/hip_bf16.h>

#define IN_CH 128
#define HID 64
#define NEG_SLOPE 0.2f
#define BSH 9            // bucket = dst >> 9  (512 dsts per bucket)
#define CAP 18432        // per-bucket capacity (mean 16384, 16-sigma slack)
#define CPT 36           // CAP / 512 entries per thread in k_binC

typedef __attribute__((ext_vector_type(8))) short short8;   // bf16x8 frag (4 VGPRs)
typedef __attribute__((ext_vector_type(4))) float floatx4;  // fp32x4 acc

__device__ inline short bfr(float f) {   // fp32 -> bf16 bits, round-nearest-even
    unsigned u = __float_as_uint(f);
    u += 0x7fffu + ((u >> 16) & 1u);
    return (short)(u >> 16);
}

// ---------------------------------------------------------------------------
// One-time: repack W (128x64 fp32) into bf16 MFMA B-fragments.
// Frag f = kt*4+nt; lane l holds B[k = kt*32 + (l>>4)*8 + j][n = nt*16 + (l&15)]
// ---------------------------------------------------------------------------
__global__ void k_prep(const float* __restrict__ W, short* __restrict__ wfrag)
{
    int idx = blockIdx.x * 256 + threadIdx.x;
    if (idx >= 1024) return;
    int f = idx >> 6, l = idx & 63;
    int kt = f >> 2, nt = f & 3;
    int k0 = kt * 32 + (l >> 4) * 8;
    int n = nt * 16 + (l & 15);
#pragma unroll
    for (int j = 0; j < 8; ++j)
        wfrag[idx * 8 + j] = bfr(W[(k0 + j) * HID + n]);
}

// ---------------------------------------------------------------------------
// h = x @ W via mfma_f32_16x16x32_bf16. Block 256 = 4 waves; each wave does
// 2 M-tiles of 16 rows. A-frags loaded straight from global in fragment
// order. C-layout: col = lane&15, row = quad*4 + reg  [m89].
// ---------------------------------------------------------------------------
__global__ __launch_bounds__(256) void k_gemm(
    const float* __restrict__ x, const short8* __restrict__ wfrag,
    const float* __restrict__ att_src, const float* __restrict__ att_dst,
    short* __restrict__ h, float* __restrict__ a_src,
    float* __restrict__ a_dst, int N)
{
    const int t = threadIdx.x;
    const int lane = t & 63;
    const int wv = t >> 6;
    const int l15 = lane & 15;
    const int quad = lane >> 4;

    short8 bf[16];
#pragma unroll
    for (int f = 0; f < 16; ++f) bf[f] = wfrag[f * 64 + lane];

    float as4[4], ad4[4];
#pragma unroll
    for (int nt = 0; nt < 4; ++nt) {
        as4[nt] = att_src[nt * 16 + l15];
        ad4[nt] = att_dst[nt * 16 + l15];
    }

    const int rowbase = blockIdx.x * 128 + wv * 32;

#pragma unroll
    for (int mt = 0; mt < 2; ++mt) {
        const int m0 = rowbase + mt * 16;
        const int rowa = m0 + l15;
        const int rowc = rowa < N ? rowa : N - 1;   // clamp loads
        const float* xp = x + (size_t)rowc * IN_CH + quad * 8;

        short8 af[4];
#pragma unroll
        for (int kt = 0; kt < 4; ++kt) {
            float4 p0 = *(const float4*)(xp + kt * 32);
            float4 p1 = *(const float4*)(xp + kt * 32 + 4);
            short8 a;
            a[0] = bfr(p0.x); a[1] = bfr(p0.y); a[2] = bfr(p0.z); a[3] = bfr(p0.w);
            a[4] = bfr(p1.x); a[5] = bfr(p1.y); a[6] = bfr(p1.z); a[7] = bfr(p1.w);
            af[kt] = a;
        }

        floatx4 acc[4];
#pragma unroll
        for (int nt = 0; nt < 4; ++nt) acc[nt] = (floatx4){0.f, 0.f, 0.f, 0.f};
#pragma unroll
        for (int kt = 0; kt < 4; ++kt)
#pragma unroll
            for (int nt = 0; nt < 4; ++nt)
                acc[nt] = __builtin_amdgcn_mfma_f32_16x16x32_bf16(
                    af[kt], bf[kt * 4 + nt], acc[nt], 0, 0, 0);

#pragma unroll
        for (int r = 0; r < 4; ++r) {
            const int row = m0 + quad * 4 + r;
            const bool ok = row < N;
            if (ok) {
#pragma unroll
                for (int nt = 0; nt < 4; ++nt)
                    h[(size_t)row * HID + nt * 16 + l15] = bfr(acc[nt][r]);
            }
            float ps = acc[0][r] * as4[0] + acc[1][r] * as4[1] +
                       acc[2][r] * as4[2] + acc[3][r] * as4[3];
            float pd = acc[0][r] * ad4[0] + acc[1][r] * ad4[1] +
                       acc[2][r] * ad4[2] + acc[3][r] * ad4[3];
#pragma unroll
            for (int m2 = 1; m2 < 16; m2 <<= 1) {
                ps += __shfl_xor(ps, m2, 64);
                pd += __shfl_xor(pd, m2, 64);
            }
            if (ok && l15 == 0) { a_src[row] = ps; a_dst[row] = pd; }
        }
    }
}

// ---------------------------------------------------------------------------
// Bucket pass: bin edges by dst>>9 into per-bucket append regions. Packed
// payload: s | (dst&511)<<17 (s < 2^17).
// ---------------------------------------------------------------------------
__global__ __launch_bounds__(256) void k_binB(
    const int* __restrict__ ei, int* __restrict__ g_cursor,
    int* __restrict__ pairs, int E, int nb)
{
    __shared__ int hist[256];
    __shared__ int base[256];
    const int t = threadIdx.x;
    hist[t] = 0;
    __syncthreads();

    int s[16], d[16];
    const int4* s4 = (const int4*)ei;
    const int4* d4 = (const int4*)(ei + E);
    const int E4 = E >> 2;
    const int q0 = blockIdx.x * 1024;
#pragma unroll
    for (int i = 0; i < 4; ++i) {
        int q = q0 + i * 256 + t;
        int4 sv = make_int4(0, 0, 0, 0);
        int4 dv = make_int4(-1, -1, -1, -1);
        if (q < E4) { sv = s4[q]; dv = d4[q]; }
        s[4 * i + 0] = sv.x; s[4 * i + 1] = sv.y; s[4 * i + 2] = sv.z; s[4 * i + 3] = sv.w;
        d[4 * i + 0] = dv.x; d[4 * i + 1] = dv.y; d[4 * i + 2] = dv.z; d[4 * i + 3] = dv.w;
    }
#pragma unroll
    for (int i = 0; i < 16; ++i)
        if (d[i] >= 0) atomicAdd(&hist[d[i] >> BSH], 1);
    __syncthreads();

    if (t < nb) base[t] = atomicAdd(&g_cursor[t], hist[t]);
    __syncthreads();
    hist[t] = 0;
    __syncthreads();

#pragma unroll
    for (int i = 0; i < 16; ++i) {
        if (d[i] < 0) continue;
        int b = d[i] >> BSH;
        int l = atomicAdd(&hist[b], 1);
        int pos = base[b] + l;
        if (pos < CAP)
            pairs[b * CAP + pos] = s[i] | ((d[i] & 511) << 17);
    }
}

// ---------------------------------------------------------------------------
// Per-bucket finalize: one block per bucket. Entries register-resident
// (single global read of pairs). LDS per-dst histogram -> block scan ->
// row_start/cnt (PADDED csr: base = b*CAP) -> scatter from registers.
// ---------------------------------------------------------------------------
__global__ __launch_bounds__(512) void k_binC(
    const int* __restrict__ pairs, const int* __restrict__ g_cursor,
    int* __restrict__ row_start, int* __restrict__ cnt,
    int* __restrict__ csr_src, int N)
{
    __shared__ int h0[512];
    __shared__ int hs[512];
    __shared__ int cur[512];
    const int t = threadIdx.x;
    const int b = blockIdx.x;
    const int d0 = b << BSH;
    int m = g_cursor[b];
    if (m > CAP) m = CAP;
    const int* pb = pairs + b * CAP;

    int ent[CPT];
#pragma unroll
    for (int k = 0; k < CPT; ++k) {
        int i = t + k * 512;
        ent[k] = (i < m) ? pb[i] : -1;
    }

    h0[t] = 0;
    __syncthreads();
#pragma unroll
    for (int k = 0; k < CPT; ++k)
        if (ent[k] >= 0) atomicAdd(&h0[ent[k] >> 17], 1);
    __syncthreads();

    hs[t] = h0[t];
    __syncthreads();
    for (int off = 1; off < 512; off <<= 1) {
        int u = (t >= off) ? hs[t - off] : 0;
        __syncthreads();
        hs[t] += u;
        __syncthreads();
    }
    const int excl = hs[t] - h0[t];
    cur[t] = excl;
    const int dd = d0 + t;
    if (dd < N) { row_start[dd] = b * CAP + excl; cnt[dd] = h0[t]; }
    __syncthreads();

    int* csr_b = csr_src + (size_t)b * CAP;
#pragma unroll
    for (int k = 0; k < CPT; ++k) {
        if (ent[k] < 0) continue;
        int p = ent[k];
        int pos = atomicAdd(&cur[p >> 17], 1);
        csr_b[pos] = p & 0x1FFFF;
    }
}

// ---------------------------------------------------------------------------
// wave-per-dst online aggregation. Fast path: complete 64-edge batches with
// the 16-iteration broadcast loop fully unrolled (16 uint2 loads in flight).
// lane = quarter q (edge j+q) x channel-group i4; 64 lanes = 4 rows/iter.
// ---------------------------------------------------------------------------
__global__ __launch_bounds__(256) void k_agg(
    const __hip_bfloat16* __restrict__ h, const float* __restrict__ a_src,
    const float* __restrict__ a_dst, const float* __restrict__ bias,
    const int* __restrict__ row_start, const int* __restrict__ cnt,
    const int* __restrict__ csr_src,
    float* __restrict__ out, float* __restrict__ inv_s, int N)
{
    const int wave = threadIdx.x >> 6;
    const int lane = threadIdx.x & 63;
    const int d = blockIdx.x * 4 + wave;
    if (d >= N) return;

    const int q  = lane >> 4;
    const int i4 = lane & 15;

    const float ad = a_dst[d];
    const int start = row_start[d];
    const int end = start + cnt[d];

    const uint2* h2 = (const uint2*)h;

    float psum = 0.f;
    float4 acc = make_float4(0.f, 0.f, 0.f, 0.f);

    int b = start;
    for (; b + 64 <= end; b += 64) {          // full batches
        int s = csr_src[b + lane];
        float v = a_src[s] + ad;
        v = v > 0.f ? v : NEG_SLOPE * v;
        float e = __expf(v);
        psum += e;
#pragma unroll
        for (int j = 0; j < 64; j += 4) {
            const int sj = __shfl(s, j + q, 64);
            const float ej = __shfl(e, j + q, 64);
            uint2 u = h2[(size_t)sj * 16 + i4];
            acc.x = fmaf(ej, __uint_as_float(u.x << 16), acc.x);
            acc.y = fmaf(ej, __uint_as_float(u.x & 0xffff0000u), acc.y);
            acc.z = fmaf(ej, __uint_as_float(u.y << 16), acc.z);
            acc.w = fmaf(ej, __uint_as_float(u.y & 0xffff0000u), acc.w);
        }
    }
    if (b < end) {                             // tail
        int idx = b + lane;
        int s = 0;
        float e = 0.f;
        if (idx < end) {
            s = csr_src[idx];
            float v = a_src[s] + ad;
            v = v > 0.f ? v : NEG_SLOPE * v;
            e = __expf(v);
            psum += e;
        }
        const int m = end - b;
        for (int j = 0; j < m; j += 4) {
            const int sj = __shfl(s, j + q, 64);
            const float ej = __shfl(e, j + q, 64);
            uint2 u = h2[(size_t)sj * 16 + i4];
            acc.x = fmaf(ej, __uint_as_float(u.x << 16), acc.x);
            acc.y = fmaf(ej, __uint_as_float(u.x & 0xffff0000u), acc.y);
            acc.z = fmaf(ej, __uint_as_float(u.y << 16), acc.z);
            acc.w = fmaf(ej, __uint_as_float(u.y & 0xffff0000u), acc.w);
        }
    }

#pragma unroll
    for (int m2 = 32; m2 > 0; m2 >>= 1) psum += __shfl_xor(psum, m2, 64);

    float vs = a_src[d] + ad;
    vs = vs > 0.f ? vs : NEG_SLOPE * vs;
    const float eself = __expf(vs);
    const float inv = 1.0f / (psum + eself);
    if (lane == 0) inv_s[d] = inv;

    acc.x += __shfl_xor(acc.x, 16, 64);
    acc.y += __shfl_xor(acc.y, 16, 64);
    acc.z += __shfl_xor(acc.z, 16, 64);
    acc.w += __shfl_xor(acc.w, 16, 64);
    acc.x += __shfl_xor(acc.x, 32, 64);
    acc.y += __shfl_xor(acc.y, 32, 64);
    acc.z += __shfl_xor(acc.z, 32, 64);
    acc.w += __shfl_xor(acc.w, 32, 64);

    if (q == 0) {
        uint2 u = h2[(size_t)d * 16 + i4];
        float4 bi = ((const float4*)bias)[i4];
        float4 o;
        o.x = fmaf(eself, __uint_as_float(u.x << 16), acc.x) * inv + bi.x;
        o.y = fmaf(eself, __uint_as_float(u.x & 0xffff0000u), acc.y) * inv + bi.y;
        o.z = fmaf(eself, __uint_as_float(u.y << 16), acc.z) * inv + bi.z;
        o.w = fmaf(eself, __uint_as_float(u.y & 0xffff0000u), acc.w) * inv + bi.w;
        *(float4*)(out + (size_t)d * HID + 4 * i4) = o;
    }
}

// ---------------------------------------------------------------------------
// edge-order alpha: coalesced write; random 4B gathers into 400 KB L2 tables.
// ---------------------------------------------------------------------------
__global__ void k_alpha(const int* __restrict__ ei,
                        const float* __restrict__ a_src,
                        const float* __restrict__ a_dst,
                        const float* __restrict__ inv_s,
                        float* __restrict__ out_alpha, int E, int N)
{
    int e = blockIdx.x * 256 + threadIdx.x;
    if (e >= E + N) return;
    int s, d;
    if (e < E) { s = ei[e]; d = ei[E + e]; }
    else       { s = e - E; d = s; }
    float v = a_src[s] + a_dst[d];
    v = v > 0.f ? v : NEG_SLOPE * v;
    out_alpha[e] = __expf(v) * inv_s[d];
}

// ---------------------------------------------------------------------------
extern "C" void kernel_launch(void* const* d_in, const int* in_sizes, int n_in,
                              void* d_out, int out_size, void* d_ws, size_t ws_size,
                              hipStream_t stream)
{
    (void)n_in; (void)out_size; (void)ws_size;
    const float* x       = (const float*)d_in[0];
    const int*   ei      = (const int*)d_in[1];
    const float* W       = (const float*)d_in[2];
    const float* att_src = (const float*)d_in[3];
    const float* att_dst = (const float*)d_in[4];
    const float* bias    = (const float*)d_in[5];

    const int N = in_sizes[0] / IN_CH;   // 100000
    const int E = in_sizes[1] / 2;       // 3200000
    const int T = E + N;
    const int nb = (N + 511) >> BSH;     // 196 buckets

    // workspace layout
    __hip_bfloat16* h = (__hip_bfloat16*)d_ws;     // N*HID bf16 (12.8 MB)
    float* a_src_d = (float*)(h + (size_t)N * HID);// N
    float* a_dst_d = a_src_d + N;                  // N
    float* inv_s   = a_dst_d + N;                  // N
    int* row_start = (int*)(inv_s + N);            // N
    int* cnt       = row_start + N;                // N
    int* g_cursor  = cnt + N;                      // 256
    short* wfrag   = (short*)(g_cursor + 256);     // 8192 shorts (16 KB)
    int* pairs     = (int*)(wfrag + 8192);         // nb*CAP
    int* csr_src   = pairs + (size_t)nb * CAP;     // nb*CAP (padded)

    float* out       = (float*)d_out;              // N*HID
    float* out_alpha = out + (size_t)N * HID;      // T

    k_prep<<<4, 256, 0, stream>>>(W, wfrag);
    k_gemm<<<(N + 127) / 128, 256, 0, stream>>>(x, (const short8*)wfrag,
                                                att_src, att_dst,
                                                (short*)h, a_src_d, a_dst_d, N);
    hipMemsetAsync(g_cursor, 0, 256 * sizeof(int), stream);
    k_binB<<<(E / 4 + 1023) / 1024, 256, 0, stream>>>(ei, g_cursor, pairs, E, nb);
    k_binC<<<nb, 512, 0, stream>>>(pairs, g_cursor,
                                   row_start, cnt, csr_src, N);
    k_agg<<<(N + 3) / 4, 256, 0, stream>>>(h, a_src_d, a_dst_d, bias,
                                           row_start, cnt, csr_src,
                                           out, inv_s, N);
    k_alpha<<<(T + 255) / 256, 256, 0, stream>>>(ei, a_src_d, a_dst_d, inv_s,
                                                 out_alpha, E, N);
}